// Round 6
// baseline (728.016 us; speedup 1.0000x reference)
//
#include <hip/hip_runtime.h>
#include <hip/hip_bf16.h>

#define D 64
#define SCAN_CHUNK 2048   // 256 threads x 8 elements

typedef unsigned int uint_t;
typedef unsigned short ushort_t;

// tanh via native exp: 1 - 2/(e^{2x}+1). Robust at +-inf.
__device__ __forceinline__ float fast_tanh(float x) {
    float e2 = __expf(2.0f * x);
    return 1.0f - 2.0f / (e2 + 1.0f);
}

__device__ __forceinline__ float leaky(float x) {
    return x >= 0.0f ? x : 0.2f * x;
}

// fp32 -> bf16 round-to-nearest-even
__device__ __forceinline__ ushort_t f2bf(float x) {
    uint_t u = __float_as_uint(x);
    u += 0x7FFFu + ((u >> 16) & 1u);
    return (ushort_t)(u >> 16);
}
__device__ __forceinline__ uint_t pack2bf(float lo, float hi) {
    return (uint_t)f2bf(lo) | ((uint_t)f2bf(hi) << 16);
}
// unpack 8 bf16 (uint4) -> 8 floats
__device__ __forceinline__ void bf8_unpack(uint4 u, float* f) {
    f[0] = __uint_as_float(u.x << 16); f[1] = __uint_as_float(u.x & 0xFFFF0000u);
    f[2] = __uint_as_float(u.y << 16); f[3] = __uint_as_float(u.y & 0xFFFF0000u);
    f[4] = __uint_as_float(u.z << 16); f[5] = __uint_as_float(u.z & 0xFFFF0000u);
    f[6] = __uint_as_float(u.w << 16); f[7] = __uint_as_float(u.w & 0xFFFF0000u);
}

// ---- K1: h_trans = feat @ Watt^T + b -> htB (bf16); also emits featB (bf16) ----
__global__ __launch_bounds__(256) void k_htrans(const float* __restrict__ feat,
                                                const float* __restrict__ W,
                                                const float* __restrict__ bias,
                                                ushort_t* __restrict__ htB,
                                                ushort_t* __restrict__ featB, int N)
{
    __shared__ float Wt[D][D];       // Wt[d][c] = W[c*64+d]
    __shared__ float bsh[D];
    __shared__ float fs[32][D + 1];
    const int t = threadIdx.x;
    for (int i = t; i < D * D; i += 256) { Wt[i & 63][i >> 6] = W[i]; }
    if (t < D) bsh[t] = bias[t];
    const int cg = t & 15;
    const int rp = t >> 4;
    for (int g = 0; g < 2; ++g) {
        const int base = blockIdx.x * 64 + g * 32;
        __syncthreads();
        for (int i = t; i < 32 * D; i += 256) {
            int r = i >> 6, d = i & 63;
            int n = base + r;
            fs[r][d] = (n < N) ? feat[(size_t)n * D + d] : 0.0f;
        }
        __syncthreads();
        // emit featB for this tile (LDS -> bf16 packed)
        for (int i = t; i < 32 * 32; i += 256) {
            int r = i >> 5, dp = (i & 31) * 2;
            int n = base + r;
            if (n < N) {
                *reinterpret_cast<uint_t*>(&featB[(size_t)n * D + dp]) =
                    pack2bf(fs[r][dp], fs[r][dp + 1]);
            }
        }
        float4 acc0 = {0, 0, 0, 0}, acc1 = {0, 0, 0, 0};
        const int r0 = rp * 2, r1 = r0 + 1;
        #pragma unroll 8
        for (int d = 0; d < D; ++d) {
            const float4 w = *reinterpret_cast<const float4*>(&Wt[d][cg * 4]);
            const float f0 = fs[r0][d], f1 = fs[r1][d];
            acc0.x += f0 * w.x; acc0.y += f0 * w.y; acc0.z += f0 * w.z; acc0.w += f0 * w.w;
            acc1.x += f1 * w.x; acc1.y += f1 * w.y; acc1.z += f1 * w.z; acc1.w += f1 * w.w;
        }
        const float4 b4 = *reinterpret_cast<const float4*>(&bsh[cg * 4]);
        const int n0 = base + r0, n1 = base + r1;
        if (n0 < N) {
            uint2 o = {pack2bf(acc0.x + b4.x, acc0.y + b4.y), pack2bf(acc0.z + b4.z, acc0.w + b4.w)};
            *reinterpret_cast<uint2*>(&htB[(size_t)n0 * D + cg * 4]) = o;
        }
        if (n1 < N) {
            uint2 o = {pack2bf(acc1.x + b4.x, acc1.y + b4.y), pack2bf(acc1.z + b4.z, acc1.w + b4.w)};
            *reinterpret_cast<uint2*>(&htB[(size_t)n1 * D + cg * 4]) = o;
        }
    }
}

// ---------------- counting sort: hist -> scan -> scatter ----------------
__global__ __launch_bounds__(256) void k_hist(const int* __restrict__ dst, int* __restrict__ cnt, int E)
{
    int e = blockIdx.x * 256 + threadIdx.x;
    if (e < E) atomicAdd(&cnt[dst[e]], 1);
}

__global__ __launch_bounds__(256) void k_scan1(int* __restrict__ offs, int* __restrict__ partials, int N)
{
    __shared__ int lds[256];
    const int t = threadIdx.x;
    const int base = blockIdx.x * SCAN_CHUNK + t * 8;
    int v[8];
    #pragma unroll
    for (int i = 0; i < 8; ++i) v[i] = (base + i < N) ? offs[base + i] : 0;
    int tot = 0;
    #pragma unroll
    for (int i = 0; i < 8; ++i) { int x = v[i]; v[i] = tot; tot += x; }
    lds[t] = tot;
    __syncthreads();
    for (int off = 1; off < 256; off <<= 1) {
        int x = 0;
        if (t >= off) x = lds[t - off];
        __syncthreads();
        lds[t] += x;
        __syncthreads();
    }
    const int texc = (t == 0) ? 0 : lds[t - 1];
    #pragma unroll
    for (int i = 0; i < 8; ++i)
        if (base + i < N) offs[base + i] = v[i] + texc;
    if (t == 255) partials[blockIdx.x] = lds[255];
}

__global__ void k_scan2(int* __restrict__ partials, int NB)
{
    if (threadIdx.x == 0 && blockIdx.x == 0) {
        int run = 0;
        for (int i = 0; i < NB; ++i) { int x = partials[i]; partials[i] = run; run += x; }
    }
}

__global__ __launch_bounds__(256) void k_scan3(int* __restrict__ offs, const int* __restrict__ partials, int N)
{
    const int add = partials[blockIdx.x];
    if (add == 0) return;
    const int base = blockIdx.x * SCAN_CHUNK + threadIdx.x * 8;
    #pragma unroll
    for (int i = 0; i < 8; ++i)
        if (base + i < N) offs[base + i] += add;
}

// scatter {edge id, src} into dst-sorted order. afterwards offs[i] = end of segment i.
__global__ __launch_bounds__(256) void k_scatter(const int* __restrict__ dst,
                                                 const int* __restrict__ srcA,
                                                 int* __restrict__ offs,
                                                 int2* __restrict__ es, int E)
{
    int e = blockIdx.x * 256 + threadIdx.x;
    if (e < E) {
        int pos = atomicAdd(&offs[dst[e]], 1);
        es[pos] = make_int2(e, srcA[e]);
    }
}

// ---- K_scores: ORIGINAL edge order (er fully sequential). 8 edges/wave x 8 d-lanes ----
// expe[e] = exp(leaky(score/8))
__global__ __launch_bounds__(256) void k_scores(const int* __restrict__ src,
                                                const int* __restrict__ dst,
                                                const ushort_t* __restrict__ htB,
                                                const float* __restrict__ er,
                                                float* __restrict__ expe, int E)
{
    const int gid = blockIdx.x * 256 + threadIdx.x;
    const int lane = gid & 63;
    const int sg = lane >> 3;   // edge slot within wave 0..7
    const int dl = lane & 7;    // d-lane: dims dl*8 .. dl*8+7
    const int e = (gid >> 6) * 8 + sg;   // consecutive edges within a wave
    if (e >= E) return;
    const int s = src[e], dd = dst[e];
    float hs[8], hd[8];
    bf8_unpack(*reinterpret_cast<const uint4*>(htB + (size_t)s * D + dl * 8), hs);
    bf8_unpack(*reinterpret_cast<const uint4*>(htB + (size_t)dd * D + dl * 8), hd);
    const float4 e0 = *reinterpret_cast<const float4*>(er + (size_t)e * D + dl * 8);
    const float4 e1 = *reinterpret_cast<const float4*>(er + (size_t)e * D + dl * 8 + 4);
    float ssum = hd[0] * fast_tanh(hs[0] + e0.x)
               + hd[1] * fast_tanh(hs[1] + e0.y)
               + hd[2] * fast_tanh(hs[2] + e0.z)
               + hd[3] * fast_tanh(hs[3] + e0.w)
               + hd[4] * fast_tanh(hs[4] + e1.x)
               + hd[5] * fast_tanh(hs[5] + e1.y)
               + hd[6] * fast_tanh(hs[6] + e1.z)
               + hd[7] * fast_tanh(hs[7] + e1.w);
    ssum += __shfl_xor(ssum, 1);
    ssum += __shfl_xor(ssum, 2);
    ssum += __shfl_xor(ssum, 4);
    if (dl == 0) expe[e] = __expf(leaky(ssum * 0.125f));
}

// ---- K_agg: sorted-by-dst gather: h_neigh = (sum ex*feat)/(sum ex + 1e-9) ----
// wave per node, 8 edge-subgroups x 8 d-lanes
__global__ __launch_bounds__(256) void k_agg(const int2* __restrict__ es,
                                             const int* __restrict__ offs,
                                             const float* __restrict__ expe,
                                             const ushort_t* __restrict__ featB,
                                             float* __restrict__ hneigh, int N)
{
    const int t = threadIdx.x;
    const int lane = t & 63;
    const int n = blockIdx.x * 4 + (t >> 6);
    if (n >= N) return;
    const int sg = lane >> 3;   // edge subgroup 0..7
    const int dl = lane & 7;    // d-lane
    const int beg = (n == 0) ? 0 : offs[n - 1];
    const int end = offs[n];
    float acc[8] = {0, 0, 0, 0, 0, 0, 0, 0};
    float den = 0.0f;
    int p = beg + sg;
    int2 cur = make_int2(0, 0);
    if (p < end) cur = es[p];
    while (p < end) {
        const int pn = p + 8;
        int2 nxt = make_int2(0, 0);
        if (pn < end) nxt = es[pn];               // prefetch next indices
        const float ex = expe[cur.x];
        float f[8];
        bf8_unpack(*reinterpret_cast<const uint4*>(featB + (size_t)cur.y * D + dl * 8), f);
        den += ex;
        #pragma unroll
        for (int j = 0; j < 8; ++j) acc[j] += ex * f[j];
        cur = nxt;
        p = pn;
    }
    // combine the 8 subgroups (lanes dl, dl+8, ..., dl+56)
    #pragma unroll
    for (int m = 8; m <= 32; m <<= 1) {
        den += __shfl_xor(den, m);
        #pragma unroll
        for (int j = 0; j < 8; ++j) acc[j] += __shfl_xor(acc[j], m);
    }
    if (sg == 0) {
        const float r = __builtin_amdgcn_rcpf(den + 1e-9f);
        float4 o0 = {acc[0] * r, acc[1] * r, acc[2] * r, acc[3] * r};
        float4 o1 = {acc[4] * r, acc[5] * r, acc[6] * r, acc[7] * r};
        *reinterpret_cast<float4*>(hneigh + (size_t)n * D + dl * 8) = o0;
        *reinterpret_cast<float4*>(hneigh + (size_t)n * D + dl * 8 + 4) = o1;
    }
}

// ---------------- K4: h_out = leaky((f+hn)@W1^T + b1 + (f*hn)@W2^T + b2) ----------------
__global__ __launch_bounds__(256) void k_out(const float* __restrict__ feat,
                                             const float* __restrict__ hneigh,
                                             const float* __restrict__ W1,
                                             const float* __restrict__ b1,
                                             const float* __restrict__ W2,
                                             const float* __restrict__ b2,
                                             float* __restrict__ out, int N)
{
    __shared__ float W1t[D][D];
    __shared__ float W2t[D][D];
    __shared__ float bsum[D];
    __shared__ float ss[32][D + 1];
    __shared__ float pp[32][D + 1];
    const int t = threadIdx.x;
    for (int i = t; i < D * D; i += 256) {
        W1t[i & 63][i >> 6] = W1[i];
        W2t[i & 63][i >> 6] = W2[i];
    }
    if (t < D) bsum[t] = b1[t] + b2[t];
    const int cg = t & 15;
    const int rp = t >> 4;
    for (int g = 0; g < 2; ++g) {
        const int base = blockIdx.x * 64 + g * 32;
        __syncthreads();
        for (int i = t; i < 32 * D; i += 256) {
            int r = i >> 6, d = i & 63;
            int n = base + r;
            float f = 0.0f, hn = 0.0f;
            if (n < N) { f = feat[(size_t)n * D + d]; hn = hneigh[(size_t)n * D + d]; }
            ss[r][d] = f + hn;
            pp[r][d] = f * hn;
        }
        __syncthreads();
        float4 a0 = {0, 0, 0, 0}, a1 = {0, 0, 0, 0};
        const int r0 = rp * 2, r1 = r0 + 1;
        #pragma unroll 4
        for (int d = 0; d < D; ++d) {
            const float4 w1 = *reinterpret_cast<const float4*>(&W1t[d][cg * 4]);
            const float4 w2 = *reinterpret_cast<const float4*>(&W2t[d][cg * 4]);
            const float s0 = ss[r0][d], p0 = pp[r0][d];
            const float s1 = ss[r1][d], p1 = pp[r1][d];
            a0.x += s0 * w1.x + p0 * w2.x; a0.y += s0 * w1.y + p0 * w2.y;
            a0.z += s0 * w1.z + p0 * w2.z; a0.w += s0 * w1.w + p0 * w2.w;
            a1.x += s1 * w1.x + p1 * w2.x; a1.y += s1 * w1.y + p1 * w2.y;
            a1.z += s1 * w1.z + p1 * w2.z; a1.w += s1 * w1.w + p1 * w2.w;
        }
        const float4 b4 = *reinterpret_cast<const float4*>(&bsum[cg * 4]);
        const int n0 = base + r0, n1 = base + r1;
        if (n0 < N) {
            float4 o = {leaky(a0.x + b4.x), leaky(a0.y + b4.y), leaky(a0.z + b4.z), leaky(a0.w + b4.w)};
            *reinterpret_cast<float4*>(&out[(size_t)n0 * D + cg * 4]) = o;
        }
        if (n1 < N) {
            float4 o = {leaky(a1.x + b4.x), leaky(a1.y + b4.y), leaky(a1.z + b4.z), leaky(a1.w + b4.w)};
            *reinterpret_cast<float4*>(&out[(size_t)n1 * D + cg * 4]) = o;
        }
    }
}

extern "C" void kernel_launch(void* const* d_in, const int* in_sizes, int n_in,
                              void* d_out, int out_size, void* d_ws, size_t ws_size,
                              hipStream_t stream) {
    const int*   idx  = (const int*)d_in[0];   // (2, E) int32
    const float* feat = (const float*)d_in[1]; // (N, 64)
    const float* er   = (const float*)d_in[2]; // (E, 64)
    const float* W1   = (const float*)d_in[4];
    const float* b1   = (const float*)d_in[5];
    const float* W2   = (const float*)d_in[6];
    const float* b2   = (const float*)d_in[7];
    const float* Wa   = (const float*)d_in[8];
    const float* ba   = (const float*)d_in[9];

    const int E = in_sizes[0] / 2;
    const int N = in_sizes[1] / D;
    const int* srcI = idx;
    const int* dstI = idx + E;

    // ws: [hneigh N*64 f32 | htB N*64 bf16 | featB N*64 bf16 | es E int2 | expe E f32 |
    //      offs N i | partials 256 i]   ~71 MB
    float*    hneigh   = (float*)d_ws;
    ushort_t* htB      = (ushort_t*)(hneigh + (size_t)N * D);
    ushort_t* featB    = htB + (size_t)N * D;
    int2*     es       = (int2*)(featB + (size_t)N * D);
    float*    expe     = (float*)(es + E);
    int*      offs     = (int*)(expe + E);
    int*      partials = offs + N;

    const int NB = (N + SCAN_CHUNK - 1) / SCAN_CHUNK;

    hipMemsetAsync(offs, 0, (size_t)N * sizeof(int), stream);

    dim3 blk(256);
    k_htrans <<<dim3((N + 63) / 64), blk, 0, stream>>>(feat, Wa, ba, htB, featB, N);
    k_hist   <<<dim3((E + 255) / 256), blk, 0, stream>>>(dstI, offs, E);
    k_scan1  <<<dim3(NB), blk, 0, stream>>>(offs, partials, N);
    k_scan2  <<<dim3(1), dim3(64), 0, stream>>>(partials, NB);
    k_scan3  <<<dim3(NB), blk, 0, stream>>>(offs, partials, N);
    k_scatter<<<dim3((E + 255) / 256), blk, 0, stream>>>(dstI, srcI, offs, es, E);
    k_scores <<<dim3((E + 31) / 32), blk, 0, stream>>>(srcI, dstI, htB, er, expe, E);
    k_agg    <<<dim3((N + 3) / 4), blk, 0, stream>>>(es, offs, expe, featB, hneigh, N);
    k_out    <<<dim3((N + 63) / 64), blk, 0, stream>>>(feat, hneigh, W1, b1, W2, b2, (float*)d_out, N);
}